// Round 9
// baseline (459.878 us; speedup 1.0000x reference)
//
#include <hip/hip_runtime.h>
#include <cstdint>
#include <cstddef>

typedef unsigned short u16;
typedef __attribute__((ext_vector_type(8))) short short8;
typedef __attribute__((ext_vector_type(4))) float f32x4;

#define DIM 512
#define C2  256
#define HD  32
#define SCALE_Q 0.17677669529663689f

__device__ __forceinline__ float bf2f(u16 u){ return __uint_as_float(((unsigned)u) << 16); }
__device__ __forceinline__ u16 f2bf(float f){
  unsigned u = __float_as_uint(f);
  unsigned r = (u + 0x7FFFu + ((u >> 16) & 1u)) >> 16;
  return (u16)r;
}

__device__ __forceinline__ f32x4 mfma16(short8 a, short8 b, f32x4 c){
  return __builtin_amdgcn_mfma_f32_16x16x32_bf16(a, b, c, 0, 0, 0);
}

// async global->LDS, 16 bytes per lane; LDS dest is wave-uniform base (+lane*16 implied)
__device__ __forceinline__ void gload16(const u16* g, u16* l){
  __builtin_amdgcn_global_load_lds((const __attribute__((address_space(1))) void*)g,
                                   (__attribute__((address_space(3))) void*)l, 16, 0, 0);
}

// fast gelu: v * sigmoid(1.702 v)  (6 VALU ops; |err| vs exact erf-gelu <= ~0.02 abs)
__device__ __forceinline__ float gelu_f(float v){
  float e = __expf(-1.702f * v);
  return v * __builtin_amdgcn_rcpf(1.0f + e);
}

// ---------------- coalesced weight transpose + fp32->bf16 via LDS tile ----------------
__global__ __launch_bounds__(256) void transpose_kernel(const float* __restrict__ W,
                                                        u16* __restrict__ WT, int K, int N){
  __shared__ u16 Tl[32][33];
  int n0 = blockIdx.x * 32, k0 = blockIdx.y * 32;
  int tx = threadIdx.x & 31, ty = threadIdx.x >> 5;   // ty 0..7
#pragma unroll
  for (int i = 0; i < 4; i++){
    int k = ty * 4 + i;
    Tl[k][tx] = f2bf(W[(size_t)(k0 + k) * N + n0 + tx]);
  }
  __syncthreads();
#pragma unroll
  for (int i = 0; i < 4; i++){
    int n = ty * 4 + i;
    WT[(size_t)(n0 + n) * K + k0 + tx] = Tl[tx][n];
  }
}

// ---------------- LayerNorm over last dim (512), one wave per row; fp32 in -> bf16 out ----------------
__global__ __launch_bounds__(256) void ln_kernel(const float* __restrict__ x, const float* __restrict__ g,
                                                 const float* __restrict__ bta, u16* __restrict__ out){
  int row  = blockIdx.x * 4 + (threadIdx.x >> 6);
  int lane = threadIdx.x & 63;
  size_t base = (size_t)row * DIM + lane * 8;
  float4 v0 = *(const float4*)(x + base);
  float4 v1 = *(const float4*)(x + base + 4);
  float f[8] = {v0.x, v0.y, v0.z, v0.w, v1.x, v1.y, v1.z, v1.w};
  float s = 0.f;
#pragma unroll
  for (int j = 0; j < 8; j++) s += f[j];
#pragma unroll
  for (int m = 1; m < 64; m <<= 1) s += __shfl_xor(s, m, 64);
  float mean = s * (1.0f / DIM);
  float vs = 0.f;
#pragma unroll
  for (int j = 0; j < 8; j++){ float d = f[j] - mean; vs += d * d; }
#pragma unroll
  for (int m = 1; m < 64; m <<= 1) vs += __shfl_xor(vs, m, 64);
  float rstd = rsqrtf(vs * (1.0f / DIM) + 1e-5f);
  float4 g0 = *(const float4*)(g + lane * 8);
  float4 g1 = *(const float4*)(g + lane * 8 + 4);
  float4 b0 = *(const float4*)(bta + lane * 8);
  float4 b1 = *(const float4*)(bta + lane * 8 + 4);
  float gg[8] = {g0.x, g0.y, g0.z, g0.w, g1.x, g1.y, g1.z, g1.w};
  float bb[8] = {b0.x, b0.y, b0.z, b0.w, b1.x, b1.y, b1.z, b1.w};
  short8 o;
#pragma unroll
  for (int j = 0; j < 8; j++){
    float r = (f[j] - mean) * rstd * gg[j] + bb[j];
    o[j] = (short)f2bf(r);
  }
  *(short8*)(out + base) = o;
}

// ---------------- GEMM body, 256x256, TWO fat phases per K-tile (32-MFMA clusters) ----------------
// C[M x N] = A[M x K] @ W[K x N] (+bias, +epilogue); A bf16 RM (lda); WT bf16 [N x K] RM.
// 8 waves (2M x 4N), per-wave C = 128x64. BK=64 as two K-halves of 32.
// LDS: [2 dbuf][2 kh][256][32] per matrix = 128 KB total. global_load_lds staging,
// linear LDS dest + inverse-swizzled global source; reads slot-swizzled (conflict-free).
// MFMA operands swapped: acc = mfma(bf, af) -> lane holds C[row=l16][col=lhi*4+i].
// Per tile t: P1{read bf[8]+af[8](qm0); bar; lgkm0; 32 MFMA; bar}
//            P2{read af[8](qm1); stage B(t+2,kh0+kh1); bar; lgkm0; 32 MFMA; bar}
//            post: stage A(t+2,kh0+kh1); vmcnt(8) (0 at tail); bar.
// Safety: B last read P1-pre (lgkm0+closing bar before P2's stage issue); A last read
// P2-pre (before post-P2 stage issue); t+2 data consumed only after t+1's drain.
template<int EPI, bool OUT_BF16>
__device__ __forceinline__ void gemm8_body(
    const u16* __restrict__ A, int lda,
    const u16* __restrict__ WT,
    const float* __restrict__ bias,
    const float* R, int ldr,
    void* Cv, int ldc, int K)
{
  __shared__ u16 Al[2][2][256 * 32];
  __shared__ u16 Bl[2][2][256 * 32];
  const int tid = threadIdx.x;
  const int l   = tid & 63;
  const int w   = tid >> 6;        // wave 0..7
  const int wr  = w >> 2;          // M half
  const int wc  = w & 3;           // N quarter
  const int l16 = l & 15, lhi = l >> 4;

  // XCD-chunked swizzle (all grids have nwg % 8 == 0)
  const int gx = gridDim.x;
  int bid = blockIdx.y * gx + blockIdx.x;
  int nwg = gx * gridDim.y;
  int sw  = (nwg & 7) ? bid : ((bid & 7) * (nwg >> 3) + (bid >> 3));
  const int col0 = (sw % gx) * 256, row0 = (sw / gx) * 256;
  const int NT = K >> 6;

  // staging source: lane covers LDS row (w*16 + l/4), slot (l&3);
  // source col-group = (l&3) ^ ((l>>3)&3)  (inverse of the read swizzle)
  const int srow = w * 16 + (l >> 2);
  const int cs   = (((l & 3) ^ ((l >> 3) & 3)) * 8);
  const u16* pA = A  + (size_t)(row0 + srow) * lda + cs;
  const u16* pB = WT + (size_t)(col0 + srow) * K  + cs;
  const size_t a128 = (size_t)128 * lda, b128 = (size_t)128 * K;

  auto stageA = [&](int tt, int hh){
    if (tt < NT){
      size_t go = (size_t)tt * 64 + (size_t)hh * 32;
      gload16(pA + go,        &Al[tt & 1][hh][(w * 16) * 32]);
      gload16(pA + a128 + go, &Al[tt & 1][hh][(128 + w * 16) * 32]);
    }
  };
  auto stageB = [&](int tt, int hh){
    if (tt < NT){
      size_t go = (size_t)tt * 64 + (size_t)hh * 32;
      gload16(pB + go,        &Bl[tt & 1][hh][(w * 16) * 32]);
      gload16(pB + b128 + go, &Bl[tt & 1][hh][(128 + w * 16) * 32]);
    }
  };

  // per-lane read offset within a [256][32] region (u16 units), slot-swizzled
  const int rdo = l16 * 32 + (lhi ^ ((l16 >> 1) & 3)) * 8;

  f32x4 acc[8][4] = {};
  short8 af[8], bf[8];

  // prologue: stage tile0 AND tile1 fully; vmcnt(8) -> tile0's 8 loads landed
  stageA(0, 0); stageB(0, 0); stageA(0, 1); stageB(0, 1);
  stageA(1, 0); stageB(1, 0); stageA(1, 1); stageB(1, 1);
  asm volatile("s_waitcnt vmcnt(8)" ::: "memory");
  __builtin_amdgcn_sched_barrier(0);
  __builtin_amdgcn_s_barrier();

#define PHASE2(BC, QM, STAGES) do{                                                      \
    if ((QM) == 0){                                                                     \
      _Pragma("unroll")                                                                 \
      for (int kh = 0; kh < 2; kh++)                                                    \
        _Pragma("unroll")                                                               \
        for (int n = 0; n < 4; n++)                                                     \
          bf[kh * 4 + n] = *(const short8*)&Bl[BC][kh][(wc * 64 + n * 16) * 32 + rdo];  \
    }                                                                                   \
    _Pragma("unroll")                                                                   \
    for (int kh = 0; kh < 2; kh++)                                                      \
      _Pragma("unroll")                                                                 \
      for (int m = 0; m < 4; m++)                                                       \
        af[kh * 4 + m] = *(const short8*)&Al[BC][kh][(wr * 128 + (QM) * 64 + m * 16) * 32 + rdo]; \
    STAGES;                                                                             \
    __builtin_amdgcn_s_barrier();                                                       \
    asm volatile("s_waitcnt lgkmcnt(0)" ::: "memory");                                  \
    __builtin_amdgcn_sched_barrier(0);                                                  \
    __builtin_amdgcn_s_setprio(1);                                                      \
    _Pragma("unroll")                                                                   \
    for (int kh = 0; kh < 2; kh++)                                                      \
      _Pragma("unroll")                                                                 \
      for (int m = 0; m < 4; m++)                                                       \
        _Pragma("unroll")                                                               \
        for (int n = 0; n < 4; n++)                                                     \
          acc[(QM) * 4 + m][n] = mfma16(bf[kh * 4 + n], af[kh * 4 + m], acc[(QM) * 4 + m][n]); \
    __builtin_amdgcn_s_setprio(0);                                                      \
    __builtin_amdgcn_s_barrier();                                                       \
  }while(0)

  for (int t = 0; t < NT; t++){
    const int bc = t & 1;
    PHASE2(bc, 0, (void)0);
    PHASE2(bc, 1, (stageB(t + 2, 0), stageB(t + 2, 1)));
    stageA(t + 2, 0); stageA(t + 2, 1);
    if (t + 2 < NT) asm volatile("s_waitcnt vmcnt(8)" ::: "memory");
    else            asm volatile("s_waitcnt vmcnt(0)" ::: "memory");
    __builtin_amdgcn_sched_barrier(0);
    __builtin_amdgcn_s_barrier();
  }
#undef PHASE2

  // ---- direct vectorized epilogue: lane owns row = l16, cols = lhi*4+{0..3} per fragment ----
  float4 bvs[4];
#pragma unroll
  for (int n = 0; n < 4; n++)
    bvs[n] = *(const float4*)&bias[col0 + wc * 64 + n * 16 + lhi * 4];
#pragma unroll
  for (int mq = 0; mq < 8; mq++){
    int grow = row0 + wr * 128 + mq * 16 + l16;
#pragma unroll
    for (int n = 0; n < 4; n++){
      int gcol = col0 + wc * 64 + n * 16 + lhi * 4;
      float4 vv = { acc[mq][n][0] + bvs[n].x, acc[mq][n][1] + bvs[n].y,
                    acc[mq][n][2] + bvs[n].z, acc[mq][n][3] + bvs[n].w };
      if constexpr (EPI == 1){
        float4 rv = *(const float4*)&R[(size_t)grow * ldr + gcol];
        vv.x += rv.x; vv.y += rv.y; vv.z += rv.z; vv.w += rv.w;
      }
      if constexpr (EPI == 2){
        vv.x = gelu_f(vv.x); vv.y = gelu_f(vv.y); vv.z = gelu_f(vv.z); vv.w = gelu_f(vv.w);
      }
      if constexpr (OUT_BF16){
        ushort4 o4 = { f2bf(vv.x), f2bf(vv.y), f2bf(vv.z), f2bf(vv.w) };
        *(ushort4*)&((u16*)Cv)[(size_t)grow * ldc + gcol] = o4;
      } else {
        *(float4*)&((float*)Cv)[(size_t)grow * ldc + gcol] = vv;
      }
    }
  }
}

// named wrappers -> per-op rows in the profile
__global__ __launch_bounds__(512, 2) void gemm_qkv_kernel(const u16* A, int lda, const u16* WT,
    const float* bias, const float* R, int ldr, void* Cv, int ldc, int K){
  gemm8_body<0, true>(A, lda, WT, bias, R, ldr, Cv, ldc, K);
}
__global__ __launch_bounds__(512, 2) void gemm_proj_kernel(const u16* A, int lda, const u16* WT,
    const float* bias, const float* R, int ldr, void* Cv, int ldc, int K){
  gemm8_body<1, false>(A, lda, WT, bias, R, ldr, Cv, ldc, K);
}
__global__ __launch_bounds__(512, 2) void gemm_fc1_kernel(const u16* A, int lda, const u16* WT,
    const float* bias, const float* R, int ldr, void* Cv, int ldc, int K){
  gemm8_body<2, true>(A, lda, WT, bias, R, ldr, Cv, ldc, K);
}
__global__ __launch_bounds__(512, 2) void gemm_fc2_kernel(const u16* A, int lda, const u16* WT,
    const float* bias, const float* R, int ldr, void* Cv, int ldc, int K){
  gemm8_body<1, false>(A, lda, WT, bias, R, ldr, Cv, ldc, K);
}

// ---------------- windowed attention + LePE, one wave per (window, head) ----------------
__global__ __launch_bounds__(64) void attn_kernel(
    const u16* __restrict__ qkv, const float* __restrict__ lw,
    const float* __restrict__ lb, u16* __restrict__ out)
{
  __shared__ float Ks[64][33];
  __shared__ float Vs[64][33];
  __shared__ float Wle[32][9];
  __shared__ float Lb[32];
  int head = blockIdx.x & 7, win = blockIdx.x >> 3;
  int wx = win & 7, wy = (win >> 3) & 7, b = win >> 6;
  int l  = threadIdx.x;           // query pixel in window
  int py = l >> 3, px = l & 7;
  size_t t = (size_t)b * 4096 + (size_t)(wy * 8 + py) * 64 + (wx * 8 + px);
  const u16* base = qkv + t * 768 + head * HD;

  float q[32];
#pragma unroll
  for (int j = 0; j < 32; j += 8){
    short8 vq = *(const short8*)(base + j);
    short8 vk = *(const short8*)(base + 256 + j);
    short8 vv = *(const short8*)(base + 512 + j);
#pragma unroll
    for (int e = 0; e < 8; e++){
      q[j + e]     = bf2f((u16)vq[e]) * SCALE_Q;
      Ks[l][j + e] = bf2f((u16)vk[e]);
      Vs[l][j + e] = bf2f((u16)vv[e]);
    }
  }
  for (int i = l; i < 288; i += 64) Wle[i / 9][i % 9] = lw[(head * 32 + i / 9) * 9 + (i % 9)];
  if (l < 32) Lb[l] = lb[head * 32 + l];
  __syncthreads();

  float sc[64];
  float mx = -1e30f;
#pragma unroll
  for (int k = 0; k < 64; k++){
    float s = 0.f;
#pragma unroll
    for (int d = 0; d < 32; d++) s += q[d] * Ks[k][d];
    sc[k] = s; mx = fmaxf(mx, s);
  }
  float sum = 0.f;
#pragma unroll
  for (int k = 0; k < 64; k++){ float e = __expf(sc[k] - mx); sc[k] = e; sum += e; }
  float inv = 1.0f / sum;
  float o[32];
#pragma unroll
  for (int d = 0; d < 32; d++) o[d] = 0.f;
#pragma unroll
  for (int k = 0; k < 64; k++){
    float p = sc[k] * inv;
#pragma unroll
    for (int d = 0; d < 32; d++) o[d] += p * Vs[k][d];
  }
  // LePE: depthwise 3x3 over the 8x8 window (zero pad at window edges)
#pragma unroll
  for (int ky = 0; ky < 3; ky++){
    int yy = py + ky - 1;
    if (yy < 0 || yy >= 8) continue;
#pragma unroll
    for (int kx = 0; kx < 3; kx++){
      int xx = px + kx - 1;
      if (xx < 0 || xx >= 8) continue;
      int kp = yy * 8 + xx;
#pragma unroll
      for (int d = 0; d < 32; d++) o[d] += Wle[d][ky * 3 + kx] * Vs[kp][d];
    }
  }
  u16* op = out + t * DIM + head * HD;
#pragma unroll
  for (int d = 0; d < 32; d += 4){
    ushort4 o4 = { f2bf(o[d] + Lb[d]), f2bf(o[d + 1] + Lb[d + 1]),
                   f2bf(o[d + 2] + Lb[d + 2]), f2bf(o[d + 3] + Lb[d + 3]) };
    *(ushort4*)&op[d] = o4;
  }
}

// ---------------- full-image depthwise 3x3 on img[..., 256:], thread = channel ----------------
__global__ __launch_bounds__(256) void convloc_kernel(const u16* __restrict__ img,
    const float* __restrict__ w, u16* __restrict__ out){
  int c  = threadIdx.x;
  int pg = blockIdx.x;            // 2048 groups of 16 pixels
  int b  = pg >> 8;
  int p0 = (pg & 255) * 16;
  float wt[9];
#pragma unroll
  for (int i = 0; i < 9; i++) wt[i] = w[c * 9 + i];
  for (int pi = 0; pi < 16; pi++){
    int p = p0 + pi;
    int y = p >> 6, x = p & 63;
    float acc = 0.f;
#pragma unroll
    for (int ky = 0; ky < 3; ky++){
      int yy = y + ky - 1;
      if (yy < 0 || yy >= 64) continue;
#pragma unroll
      for (int kx = 0; kx < 3; kx++){
        int xx = x + kx - 1;
        if (xx < 0 || xx >= 64) continue;
        acc += wt[ky * 3 + kx] * bf2f(img[((size_t)b * 4096 + yy * 64 + xx) * DIM + C2 + c]);
      }
    }
    out[((size_t)b * 4096 + p) * DIM + C2 + c] = f2bf(acc);
  }
}

extern "C" void kernel_launch(void* const* d_in, const int* in_sizes, int n_in,
                              void* d_out, int out_size, void* d_ws, size_t ws_size,
                              hipStream_t stream){
  const float* x      = (const float*)d_in[0];
  const float* n1g    = (const float*)d_in[1];
  const float* n1b    = (const float*)d_in[2];
  const float* qkv_w  = (const float*)d_in[3];
  const float* qkv_b  = (const float*)d_in[4];
  const float* lepe_w = (const float*)d_in[5];
  const float* lepe_b = (const float*)d_in[6];
  const float* conv_w = (const float*)d_in[7];
  const float* proj_w = (const float*)d_in[8];
  const float* proj_b = (const float*)d_in[9];
  const float* n2g    = (const float*)d_in[10];
  const float* n2b    = (const float*)d_in[11];
  const float* fc1_w  = (const float*)d_in[12];
  const float* fc1_b  = (const float*)d_in[13];
  const float* fc2_w  = (const float*)d_in[14];
  const float* fc2_b  = (const float*)d_in[15];
  float* out = (float*)d_out;

  char* ws = (char*)d_ws;
  u16* img     = (u16*)(ws + 0);
  u16* qkvb    = (u16*)(ws + 33554432ull);
  u16* localb  = (u16*)(ws + 83886080ull);
  u16* y       = (u16*)(ws + 0);
  u16* h       = (u16*)(ws + 33554432ull);
  u16* qkv_wT  = (u16*)(ws + 167772160ull);
  u16* proj_wT = (u16*)(ws + 167772160ull + 393216ull);
  u16* fc1_wT  = (u16*)(ws + 167772160ull + 393216ull + 524288ull);
  u16* fc2_wT  = (u16*)(ws + 167772160ull + 393216ull + 524288ull + 2097152ull);
  float* xa    = (float*)d_out;

  { dim3 g(24, 8);  transpose_kernel<<<g, 256, 0, stream>>>(qkv_w,  qkv_wT,  256, 768);  }
  { dim3 g(16, 16); transpose_kernel<<<g, 256, 0, stream>>>(proj_w, proj_wT, 512, 512);  }
  { dim3 g(64, 16); transpose_kernel<<<g, 256, 0, stream>>>(fc1_w,  fc1_wT,  512, 2048); }
  { dim3 g(16, 64); transpose_kernel<<<g, 256, 0, stream>>>(fc2_w,  fc2_wT,  2048, 512); }

  ln_kernel<<<8192, 256, 0, stream>>>(x, n1g, n1b, img);

  dim3 gq(3, 128);   // x = col-blocks (256 wide), y = row-blocks
  gemm_qkv_kernel<<<gq, 512, 0, stream>>>(img, DIM, qkv_wT, qkv_b, nullptr, 0, qkvb, 768, 256);

  attn_kernel<<<4096, 64, 0, stream>>>(qkvb, lepe_w, lepe_b, localb);
  convloc_kernel<<<2048, 256, 0, stream>>>(img, conv_w, localb);

  dim3 gp(2, 128);
  gemm_proj_kernel<<<gp, 512, 0, stream>>>(localb, DIM, proj_wT, proj_b, x, DIM, xa, DIM, 512);

  ln_kernel<<<8192, 256, 0, stream>>>(xa, n2g, n2b, y);

  dim3 g1(8, 128);
  gemm_fc1_kernel<<<g1, 512, 0, stream>>>(y, DIM, fc1_wT, fc1_b, nullptr, 0, h, 2048, 512);

  dim3 g2(2, 128);
  gemm_fc2_kernel<<<g2, 512, 0, stream>>>(h, 2048, fc2_wT, fc2_b, xa, DIM, out, DIM, 2048);
}